// Round 4
// baseline (320.727 us; speedup 1.0000x reference)
//
#include <hip/hip_runtime.h>
#include <hip/hip_fp16.h>

// R4: reformulate as GEMM. out[s,n] = sum_c w0*comp[c][n+d] + w1*comp[c][n+d+1]
//   = sum_k A[s,k] * G[k,n],  k = (c, e) with e = integer shift in [-17,17].
// A[s, c*40 + (d+17)]   = w0 (f16, compensated rounding)
// A[s, c*40 + (d+1+17)] = w1 (f16)
// G[(c,e), n] = f16(comp[c][n+e]) with boundary zeros (== reference masks).
// G's half-rounding is IDENTICAL to the previous kernels' half comps; the
// only new error is f16 weights, mitigated by w0h = rn(ct - float(w1h)).
// K = 8*40 = 320 (35 used slots + 5 zero-pad per c) = 5 x BK64 MFMA steps.
// Compute: 21.5 GFLOP -> ~3us of matrix pipe; floor = 134MB output write.
// Workspace: Gt (n-major, 1.31MB) + A (10.49MB) = 11.8MB in d_ws, built by
// 3 tiny pre-kernels. If ws_size too small, fall back to the R3 kernel.

namespace {
constexpr int kS = 16384;
constexpr int kN = 2048;
constexpr int kC = 8;
constexpr int kK = 320;             // 8 comps * 40 slots
constexpr int kSlots = 40;          // per-c k-slots; e = t-17, t<35 used
constexpr size_t kGtBytes = (size_t)kN * kK * 2;        // 1,310,720
constexpr size_t kABytes  = (size_t)kS * kK * 2;        // 10,485,760
constexpr size_t kWsNeed  = kGtBytes + kABytes;         // 11,796,480

typedef _Float16 f16x8 __attribute__((ext_vector_type(8)));
typedef float    f32x4 __attribute__((ext_vector_type(4)));

// ---------------- pre-kernel 1: zero A ----------------
__global__ __launch_bounds__(256)
void zeroA_kernel(uint4* __restrict__ a4) {
    const int idx = blockIdx.x * 256 + threadIdx.x;
    const int n4  = (int)(kABytes / 16);
    if (idx < n4) a4[idx] = make_uint4(0u, 0u, 0u, 0u);
}

// ---------------- pre-kernel 2: build Gt[n][320] ----------------
// thread: c = tid>>11, n = tid&2047. Loads comp[c][n+e] coalesced per e.
__global__ __launch_bounds__(256)
void buildG_kernel(const float* __restrict__ comps, __half* __restrict__ Gt) {
    const int tid = blockIdx.x * 256 + threadIdx.x;   // 0..16383
    const int c = tid >> 11;
    const int n = tid & 2047;
    const float* src = comps + c * kN;

    uint32_t w[kSlots / 2];
    #pragma unroll
    for (int t2 = 0; t2 < kSlots / 2; ++t2) {
        uint32_t pk = 0;
        #pragma unroll
        for (int h = 0; h < 2; ++h) {
            const int t = 2 * t2 + h;
            float v = 0.f;
            if (t < 35) {
                const int j = n + (t - 17);
                if (j >= 0 && j < kN) v = src[j];
            }
            const __half hv = __float2half_rn(v);
            pk |= (uint32_t)__half_as_ushort(hv) << (16 * h);
        }
        w[t2] = pk;
    }
    uint4* dst = reinterpret_cast<uint4*>(Gt + (size_t)n * kK + c * kSlots);
    #pragma unroll
    for (int i = 0; i < kSlots / 8; ++i)
        dst[i] = make_uint4(w[4 * i], w[4 * i + 1], w[4 * i + 2], w[4 * i + 3]);
}

// ---------------- pre-kernel 3: scatter weights into A ----------------
__global__ __launch_bounds__(256)
void buildA_kernel(const float* __restrict__ contrib,
                   const float* __restrict__ shift,
                   __half* __restrict__ A) {
    const int tid = blockIdx.x * 256 + threadIdx.x;   // 0..131071
    const int s = tid >> 3;
    const int c = tid & 7;
    const float ctv = contrib[(size_t)s * kC + c];
    const float sv  = shift[(size_t)s * kC + c];
    float fl = floorf(sv);
    int d = (int)fl;
    d = d < -17 ? -17 : (d > 16 ? 16 : d);            // |shift|>17 ~ never
    const float fr = sv - (float)d;
    const __half w1h = __float2half_rn(ctv * fr);
    const __half w0h = __float2half_rn(ctv - __half2float(w1h)); // compensated
    __half* row = A + (size_t)s * kK + c * kSlots;
    row[d + 17] = w0h;
    row[d + 18] = w1h;
}

// ---------------- main GEMM: [16384 x 320] x [320 x 2048] ----------------
// 128x128 tile, BK=64 (5 steps), 256 threads = 4 waves (2x2 of 64x64).
// LDS tiles [128 rows][64 halves], 16B slots XOR-swizzled by (row&7):
// LDS[r][t] holds X[r][t ^ (r&7)] -> frag ds_read_b128 lands 2-way (free).
__global__ __launch_bounds__(256, 2)
void gemm_kernel(const __half* __restrict__ A, const __half* __restrict__ Gt,
                 float* __restrict__ out) {
    __shared__ __align__(16) __half At[128 * 64];
    __shared__ __align__(16) __half Bt[128 * 64];

    const int tid = threadIdx.x;
    const int bm = blockIdx.x >> 4;       // 128 m-tiles
    const int bn = blockIdx.x & 15;       // 16 n-tiles (inner -> A-panel L2 reuse)
    const int s0 = bm * 128, n0 = bn * 128;

    // staging: 4 rounds x (A,B); 8 threads cover one 128B row-chunk.
    const int rbase = tid >> 3;           // 0..31
    const int t8    = tid & 7;
    const __half* srcA[4];
    const __half* srcB[4];
    int dst[4];
    #pragma unroll
    for (int q = 0; q < 4; ++q) {
        const int rr = q * 32 + rbase;
        const int slot = t8 ^ (rr & 7);   // pre-swizzled SOURCE, linear dest
        srcA[q] = A  + (size_t)(s0 + rr) * kK + slot * 8;
        srcB[q] = Gt + (size_t)(n0 + rr) * kK + slot * 8;
        dst[q]  = rr * 64 + t8 * 8;       // half index
    }

    const int lane = tid & 63, wave = tid >> 6;
    const int wm = (wave >> 1) * 64, wn = (wave & 1) * 64;
    const int l15 = lane & 15, l4 = lane >> 4, p = lane & 7;
    // loop-invariant ds_read offsets (half index); slot = (ks*4+l4)^p
    const int aOff0 = (wm + l15) * 64 + ((l4)     ^ p) * 8;
    const int aOff1 = (wm + l15) * 64 + ((4 + l4) ^ p) * 8;
    const int bOff0 = (wn + l15) * 64 + ((l4)     ^ p) * 8;
    const int bOff1 = (wn + l15) * 64 + ((4 + l4) ^ p) * 8;

    f32x4 acc[4][4];
    #pragma unroll
    for (int mi = 0; mi < 4; ++mi)
        #pragma unroll
        for (int ni = 0; ni < 4; ++ni)
            acc[mi][ni] = f32x4{0.f, 0.f, 0.f, 0.f};

    // T14 split: loads issued before compute so HBM/L2 latency hides under MFMA
    uint4 ta[4], tb[4];
    #pragma unroll
    for (int q = 0; q < 4; ++q) {
        ta[q] = *reinterpret_cast<const uint4*>(srcA[q]);
        tb[q] = *reinterpret_cast<const uint4*>(srcB[q]);
    }

    #pragma unroll 1
    for (int step = 0; step < 5; ++step) {
        #pragma unroll
        for (int q = 0; q < 4; ++q) {
            *reinterpret_cast<uint4*>(&At[dst[q]]) = ta[q];
            *reinterpret_cast<uint4*>(&Bt[dst[q]]) = tb[q];
        }
        __syncthreads();
        if (step < 4) {
            #pragma unroll
            for (int q = 0; q < 4; ++q) {
                srcA[q] += 64; srcB[q] += 64;
                ta[q] = *reinterpret_cast<const uint4*>(srcA[q]);
                tb[q] = *reinterpret_cast<const uint4*>(srcB[q]);
            }
        }
        #pragma unroll
        for (int ks = 0; ks < 2; ++ks) {
            const int ao = ks ? aOff1 : aOff0;
            const int bo = ks ? bOff1 : bOff0;
            f16x8 af[4], bf[4];
            #pragma unroll
            for (int mi = 0; mi < 4; ++mi)
                af[mi] = *reinterpret_cast<const f16x8*>(&At[ao + mi * 1024]);
            #pragma unroll
            for (int ni = 0; ni < 4; ++ni)
                bf[ni] = *reinterpret_cast<const f16x8*>(&Bt[bo + ni * 1024]);
            #pragma unroll
            for (int mi = 0; mi < 4; ++mi)
                #pragma unroll
                for (int ni = 0; ni < 4; ++ni)
                    acc[mi][ni] = __builtin_amdgcn_mfma_f32_16x16x32_f16(
                        af[mi], bf[ni], acc[mi][ni], 0, 0, 0);
        }
        __syncthreads();
    }

    // epilogue: C/D layout col=lane&15, row=(lane>>4)*4+reg  [m89-verified]
    #pragma unroll
    for (int mi = 0; mi < 4; ++mi) {
        #pragma unroll
        for (int v = 0; v < 4; ++v) {
            float* orow = out + (size_t)(s0 + wm + mi * 16 + l4 * 4 + v) * kN
                              + n0 + wn + l15;
            #pragma unroll
            for (int ni = 0; ni < 4; ++ni) orow[ni * 16] = acc[mi][ni][v];
        }
    }
}

// ---------------- R3 fallback (known-passing, 117us/dispatch) ----------------
constexpr int kMf     = 16;
constexpr int kBlockF = 512;
constexpr int kPadH  = 32;
constexpr int kUnits = 1057;
constexpr int kRowStride = 1192;
__device__ __forceinline__ int swz(int u) { return u + (u >> 3); }

__global__ __launch_bounds__(kBlockF, 8)
void smf_kernel(const float* __restrict__ comps,
                const float* __restrict__ contrib,
                const float* __restrict__ shift,
                float* __restrict__ out)
{
    __shared__ uint32_t ldsU[kC * kRowStride];
    __shared__ float    ctLds[kMf * kC];
    __shared__ float    shLds[kMf * kC];

    const int tid = threadIdx.x;
    const int s0  = blockIdx.x * kMf;

    for (int c = 0; c < kC; ++c) {
        const float* src = comps + c * kN;
        uint32_t* dstp = ldsU + c * kRowStride;
        for (int u = tid; u < kUnits; u += kBlockF) {
            const int j = 2 * u - kPadH;
            float2 v = make_float2(0.f, 0.f);
            if (j >= 0 && j < kN - 1) v = *reinterpret_cast<const float2*>(src + j);
            __half2 h2 = __floats2half2_rn(v.x, v.y);
            dstp[swz(u)] = *reinterpret_cast<const uint32_t*>(&h2);
        }
    }
    for (int tt = tid; tt < (kMf * kC) / 2; tt += kBlockF) {
        if (tt < (kMf * kC) / 4) {
            reinterpret_cast<float4*>(ctLds)[tt] =
                reinterpret_cast<const float4*>(contrib + (size_t)s0 * kC)[tt];
        } else {
            const int t2 = tt - (kMf * kC) / 4;
            reinterpret_cast<float4*>(shLds)[t2] =
                reinterpret_cast<const float4*>(shift + (size_t)s0 * kC)[t2];
        }
    }
    __syncthreads();

    const int q = tid >> 8;
    const int t = tid & 255;

    #pragma unroll 1
    for (int r = 0; r < kMf / 2; ++r) {
        const int si = q * (kMf / 2) + r;
        const int s  = s0 + si;
        const float4 ccA = *reinterpret_cast<const float4*>(ctLds + si * kC);
        const float4 ccB = *reinterpret_cast<const float4*>(ctLds + si * kC + 4);
        const float4 csA = *reinterpret_cast<const float4*>(shLds + si * kC);
        const float4 csB = *reinterpret_cast<const float4*>(shLds + si * kC + 4);
        const float ct[8] = {ccA.x, ccA.y, ccA.z, ccA.w, ccB.x, ccB.y, ccB.z, ccB.w};
        const float sh[8] = {csA.x, csA.y, csA.z, csA.w, csB.x, csB.y, csB.z, csB.w};
        float accA[4], accB[4];
        #pragma unroll
        for (int k = 0; k < 4; ++k) { accA[k] = 0.f; accB[k] = 0.f; }
        #pragma unroll
        for (int c = 0; c < kC; ++c) {
            const float fl = floorf(sh[c]);
            const float fr = sh[c] - fl;
            int d = (int)fl;
            d = d < -31 ? -31 : (d > 31 ? 31 : d);
            const float w1 = ct[c] * fr;
            const float w0 = ct[c] - w1;
            const int a   = 4 * t + d + kPadH;
            const int u0  = a >> 1;
            const bool odd = (a & 1) != 0;
            const uint32_t* row = ldsU + c * kRowStride;
            const uint32_t yA0 = row[swz(u0 + 0)];
            const uint32_t yA1 = row[swz(u0 + 1)];
            const uint32_t yA2 = row[swz(u0 + 2)];
            const uint32_t yB0 = row[swz(u0 + 512)];
            const uint32_t yB1 = row[swz(u0 + 513)];
            const uint32_t yB2 = row[swz(u0 + 514)];
            const uint32_t zA0 = odd ? __builtin_amdgcn_alignbit(yA1, yA0, 16) : yA0;
            const uint32_t zA1 = odd ? __builtin_amdgcn_alignbit(yA2, yA1, 16) : yA1;
            const uint32_t zA2 = odd ? (yA2 >> 16) : yA2;
            const uint32_t zB0 = odd ? __builtin_amdgcn_alignbit(yB1, yB0, 16) : yB0;
            const uint32_t zB1 = odd ? __builtin_amdgcn_alignbit(yB2, yB1, 16) : yB1;
            const uint32_t zB2 = odd ? (yB2 >> 16) : yB2;
            const float2 fA0 = __half22float2(*reinterpret_cast<const __half2*>(&zA0));
            const float2 fA1 = __half22float2(*reinterpret_cast<const __half2*>(&zA1));
            const float2 fA2 = __half22float2(*reinterpret_cast<const __half2*>(&zA2));
            const float2 fB0 = __half22float2(*reinterpret_cast<const __half2*>(&zB0));
            const float2 fB1 = __half22float2(*reinterpret_cast<const __half2*>(&zB1));
            const float2 fB2 = __half22float2(*reinterpret_cast<const __half2*>(&zB2));
            accA[0] += w0 * fA0.x + w1 * fA0.y;
            accA[1] += w0 * fA0.y + w1 * fA1.x;
            accA[2] += w0 * fA1.x + w1 * fA1.y;
            accA[3] += w0 * fA1.y + w1 * fA2.x;
            accB[0] += w0 * fB0.x + w1 * fB0.y;
            accB[1] += w0 * fB0.y + w1 * fB1.x;
            accB[2] += w0 * fB1.x + w1 * fB1.y;
            accB[3] += w0 * fB1.y + w1 * fB2.x;
        }
        float* orow = out + (size_t)s * kN;
        *reinterpret_cast<float4*>(orow + 4 * t) =
            make_float4(accA[0], accA[1], accA[2], accA[3]);
        *reinterpret_cast<float4*>(orow + 1024 + 4 * t) =
            make_float4(accB[0], accB[1], accB[2], accB[3]);
    }
}
} // namespace

extern "C" void kernel_launch(void* const* d_in, const int* in_sizes, int n_in,
                              void* d_out, int out_size, void* d_ws, size_t ws_size,
                              hipStream_t stream) {
    const float* comps   = (const float*)d_in[1];
    const float* contrib = (const float*)d_in[2];
    const float* shiftp  = (const float*)d_in[3];
    float* out = (float*)d_out;

    if (ws_size >= kWsNeed && d_ws != nullptr) {
        __half* Gt = (__half*)d_ws;
        __half* A  = (__half*)((char*)d_ws + kGtBytes);
        zeroA_kernel<<<dim3((int)(kABytes / 16 / 256)), dim3(256), 0, stream>>>(
            (uint4*)A);
        buildG_kernel<<<dim3((kC * kN) / 256), dim3(256), 0, stream>>>(comps, Gt);
        buildA_kernel<<<dim3((kS * kC) / 256), dim3(256), 0, stream>>>(contrib, shiftp, A);
        gemm_kernel<<<dim3((kS / 128) * (kN / 128)), dim3(256), 0, stream>>>(A, Gt, out);
    } else {
        smf_kernel<<<dim3(kS / kMf), dim3(kBlockF), 0, stream>>>(comps, contrib, shiftp, out);
    }
}

// Round 6
// 294.184 us; speedup vs baseline: 1.0902x; 1.0902x over previous
//
#include <hip/hip_runtime.h>
#include <hip/hip_fp16.h>

// R6 = R5 with the compile fix: __builtin_nontemporal_store requires a
// native vector type, not HIP's float4 class -> use ext_vector f32x4 for
// the LDS-bounce read + stream store. Logic otherwise identical to R5.
//
// R5 theory (untested due to compile error):
// R4 dispatch was HBM-bound at 639 MB (4.4x ideal):
//   - A re-fetched 16x (170 MB): concurrent write-allocate footprint
//     (4 MB/XCD) thrashed L2 -> zero cross-tile A reuse;
//   - WRITE 453 MB (3.4x output): scattered 4B epilogue + thrash.
// Fix: (1) A-tile built IN LDS per block from contrib/shift (A never in
// HBM). Wave preloads its 20 A-frags into regs once; K-loop reads only B
// from LDS. (2) 256 blocks (1/CU), block = 64 rows x 2048 cols in 16
// n-steps of 128; Gt (1.3 MB, pre-kernel, R4-verified) stays L2-resident.
// (3) Epilogue bounces acc through LDS and streams full-line f32x4 with
// nontemporal stores. Math identical to R4 (refcheck-passed, 0 conflicts).

namespace {
constexpr int kS = 16384;
constexpr int kN = 2048;
constexpr int kC = 8;
constexpr int kK = 320;             // 8 comps * 40 slots
constexpr int kSlots = 40;          // 16B (8-half) slots per K-row
constexpr size_t kGtBytes = (size_t)kN * kK * 2;   // 1,310,720
constexpr size_t kWsNeed  = kGtBytes;

typedef _Float16 f16x8 __attribute__((ext_vector_type(8)));
typedef float    f32x4 __attribute__((ext_vector_type(4)));

// ---------------- pre-kernel: build Gt[n][320] (R4-verified) ----------------
__global__ __launch_bounds__(256)
void buildG_kernel(const float* __restrict__ comps, __half* __restrict__ Gt) {
    const int tid = blockIdx.x * 256 + threadIdx.x;   // 0..16383
    const int c = tid >> 11;
    const int n = tid & 2047;
    const float* src = comps + c * kN;

    uint32_t w[kSlots / 2];
    #pragma unroll
    for (int t2 = 0; t2 < kSlots / 2; ++t2) {
        uint32_t pk = 0;
        #pragma unroll
        for (int h = 0; h < 2; ++h) {
            const int t = 2 * t2 + h;
            float v = 0.f;
            if (t < 35) {
                const int j = n + (t - 17);
                if (j >= 0 && j < kN) v = src[j];
            }
            const __half hv = __float2half_rn(v);
            pk |= (uint32_t)__half_as_ushort(hv) << (16 * h);
        }
        w[t2] = pk;
    }
    uint4* dst = reinterpret_cast<uint4*>(Gt + (size_t)n * kK + c * kSlots);
    #pragma unroll
    for (int i = 0; i < kSlots / 8; ++i)
        dst[i] = make_uint4(w[4 * i], w[4 * i + 1], w[4 * i + 2], w[4 * i + 3]);
}

// ---------------- main kernel: 256 blocks x 512 threads ----------------
// Block: 64 s-rows x 2048 n-cols (16 n-steps of 128).
// Waves: 8 = 2m x 4n, wave tile 32x32, frags 2x2 of 16x16, K=320 (10 ks).
__global__ __launch_bounds__(512, 2)
void gemm_kernel(const float* __restrict__ contrib,
                 const float* __restrict__ shift,
                 const __half* __restrict__ Gt,
                 float* __restrict__ out)
{
    __shared__ __half Atile[64 * kK];    // 40960 B, slot-swizzled
    __shared__ __half Btile[128 * kK];   // 81920 B, slot-swizzled
    __shared__ float  outB[64 * 136];    // 34816 B (pad 136 -> 2-way writes)
    // total 157696 B <= 160 KiB, 1 block/CU

    const int tid = threadIdx.x;
    const int s0  = blockIdx.x * 64;

    // ---- issue panel-0 global loads early (T14) ----
    // thread: rr = row in panel (0..127), sb in 0..3; slots sb+4q (q=0..9).
    const int rr = tid >> 2;
    const int sb = tid & 3;
    const int xw = rr & 7;               // staging-dst XOR
    uint4 tb[10];
    {
        const __half* g = Gt + (size_t)rr * kK;
        #pragma unroll
        for (int q = 0; q < 10; ++q)
            tb[q] = *reinterpret_cast<const uint4*>(g + (sb + 4 * q) * 8);
    }

    // ---- build A-tile in LDS (zero + scatter) ----
    #pragma unroll
    for (int i = 0; i < 5; ++i)          // 64*320 halves = 2560 uint4
        reinterpret_cast<uint4*>(Atile)[i * 512 + tid] = make_uint4(0u,0u,0u,0u);
    __syncthreads();
    {
        const int sr = tid >> 3;         // 0..63
        const int c  = tid & 7;
        const float ctv = contrib[(size_t)(s0 + sr) * kC + c];
        const float sv  = shift[(size_t)(s0 + sr) * kC + c];
        int d = (int)floorf(sv);
        d = d < -17 ? -17 : (d > 16 ? 16 : d);
        const float fr = sv - (float)d;
        const __half w1h = __float2half_rn(ctv * fr);
        const __half w0h = __float2half_rn(ctv - __half2float(w1h)); // compensated
        const int h0 = c * kSlots + d + 17;
        const int h1 = h0 + 1;
        const int x  = sr & 7;
        Atile[sr * kK + (((h0 >> 3) ^ x) << 3) + (h0 & 7)] = w0h;
        Atile[sr * kK + (((h1 >> 3) ^ x) << 3) + (h1 & 7)] = w1h;
    }
    __syncthreads();

    // ---- preload this wave's A-frags into registers (read once, reuse 16x) ----
    const int lane = tid & 63;
    const int wave = tid >> 6;
    const int wm = (wave >> 2) * 32;     // 0 / 32
    const int wn = (wave & 3) * 32;      // 0 / 32 / 64 / 96
    const int l15 = lane & 15, l4 = lane >> 4;

    f16x8 af[10][2];
    #pragma unroll
    for (int mi = 0; mi < 2; ++mi) {
        const int r = wm + mi * 16 + l15;
        const int x = r & 7;
        #pragma unroll
        for (int ks = 0; ks < 10; ++ks) {
            const int sl = (ks * 4 + l4) ^ x;
            af[ks][mi] = *reinterpret_cast<const f16x8*>(&Atile[r * kK + sl * 8]);
        }
    }

    // B-frag loop invariants
    const int rB0 = wn + l15, rB1 = rB0 + 16;
    const int xB0 = rB0 & 7,  xB1 = rB1 & 7;
    const int bBase0 = rB0 * kK, bBase1 = rB1 * kK;

    #pragma unroll 1
    for (int step = 0; step < 16; ++step) {
        __syncthreads();   // prior Btile/outB reads done (A preload on step 0)

        // staged regs -> Btile (swizzled dst; 2 lanes/bank = free)
        {
            __half* drow = Btile + rr * kK;
            #pragma unroll
            for (int q = 0; q < 10; ++q) {
                const int sl = (sb + 4 * q) ^ xw;
                *reinterpret_cast<uint4*>(drow + sl * 8) = tb[q];
            }
        }
        __syncthreads();

        // issue next-panel loads (consumed at next iteration's top)
        if (step < 15) {
            const __half* g = Gt + ((size_t)(step + 1) * 128 + rr) * kK;
            #pragma unroll
            for (int q = 0; q < 10; ++q)
                tb[q] = *reinterpret_cast<const uint4*>(g + (sb + 4 * q) * 8);
        }

        // ---- K-loop: B from LDS, A from regs ----
        f32x4 acc00 = {0.f,0.f,0.f,0.f}, acc01 = {0.f,0.f,0.f,0.f};
        f32x4 acc10 = {0.f,0.f,0.f,0.f}, acc11 = {0.f,0.f,0.f,0.f};
        #pragma unroll
        for (int ks = 0; ks < 10; ++ks) {
            const int kq = ks * 4 + l4;
            const f16x8 b0 = *reinterpret_cast<const f16x8*>(
                &Btile[bBase0 + ((kq ^ xB0) << 3)]);
            const f16x8 b1 = *reinterpret_cast<const f16x8*>(
                &Btile[bBase1 + ((kq ^ xB1) << 3)]);
            acc00 = __builtin_amdgcn_mfma_f32_16x16x32_f16(af[ks][0], b0, acc00, 0,0,0);
            acc01 = __builtin_amdgcn_mfma_f32_16x16x32_f16(af[ks][0], b1, acc01, 0,0,0);
            acc10 = __builtin_amdgcn_mfma_f32_16x16x32_f16(af[ks][1], b0, acc10, 0,0,0);
            acc11 = __builtin_amdgcn_mfma_f32_16x16x32_f16(af[ks][1], b1, acc11, 0,0,0);
        }

        // ---- epilogue: acc -> outB (C/D: col=lane&15, row=(lane>>4)*4+v) ----
        #pragma unroll
        for (int v = 0; v < 4; ++v) {
            outB[(wm +  0 + l4*4 + v) * 136 + wn +  0 + l15] = acc00[v];
            outB[(wm +  0 + l4*4 + v) * 136 + wn + 16 + l15] = acc01[v];
            outB[(wm + 16 + l4*4 + v) * 136 + wn +  0 + l15] = acc10[v];
            outB[(wm + 16 + l4*4 + v) * 136 + wn + 16 + l15] = acc11[v];
        }
        __syncthreads();

        // ---- stream: full-line nontemporal f32x4 stores ----
        const int n0 = step * 128;
        #pragma unroll
        for (int k2 = 0; k2 < 4; ++k2) {
            const int f   = k2 * 512 + tid;   // 0..2047 float4s
            const int row = f >> 5;           // 32 f4 per 128-col row
            const int c4  = f & 31;
            const f32x4 val = *reinterpret_cast<const f32x4*>(&outB[row * 136 + c4 * 4]);
            __builtin_nontemporal_store(val,
                reinterpret_cast<f32x4*>(out + (size_t)(s0 + row) * kN + n0 + c4 * 4));
        }
    }
}

// ---------------- R3 fallback (known-passing) ----------------
constexpr int kMf     = 16;
constexpr int kBlockF = 512;
constexpr int kPadH  = 32;
constexpr int kUnits = 1057;
constexpr int kRowStride = 1192;
__device__ __forceinline__ int swz(int u) { return u + (u >> 3); }

__global__ __launch_bounds__(kBlockF, 8)
void smf_kernel(const float* __restrict__ comps,
                const float* __restrict__ contrib,
                const float* __restrict__ shift,
                float* __restrict__ out)
{
    __shared__ uint32_t ldsU[kC * kRowStride];
    __shared__ float    ctLds[kMf * kC];
    __shared__ float    shLds[kMf * kC];

    const int tid = threadIdx.x;
    const int s0  = blockIdx.x * kMf;

    for (int c = 0; c < kC; ++c) {
        const float* src = comps + c * kN;
        uint32_t* dstp = ldsU + c * kRowStride;
        for (int u = tid; u < kUnits; u += kBlockF) {
            const int j = 2 * u - kPadH;
            float2 v = make_float2(0.f, 0.f);
            if (j >= 0 && j < kN - 1) v = *reinterpret_cast<const float2*>(src + j);
            __half2 h2 = __floats2half2_rn(v.x, v.y);
            dstp[swz(u)] = *reinterpret_cast<const uint32_t*>(&h2);
        }
    }
    for (int tt = tid; tt < (kMf * kC) / 2; tt += kBlockF) {
        if (tt < (kMf * kC) / 4) {
            reinterpret_cast<float4*>(ctLds)[tt] =
                reinterpret_cast<const float4*>(contrib + (size_t)s0 * kC)[tt];
        } else {
            const int t2 = tt - (kMf * kC) / 4;
            reinterpret_cast<float4*>(shLds)[t2] =
                reinterpret_cast<const float4*>(shift + (size_t)s0 * kC)[t2];
        }
    }
    __syncthreads();

    const int q = tid >> 8;
    const int t = tid & 255;

    #pragma unroll 1
    for (int r = 0; r < kMf / 2; ++r) {
        const int si = q * (kMf / 2) + r;
        const int s  = s0 + si;
        const float4 ccA = *reinterpret_cast<const float4*>(ctLds + si * kC);
        const float4 ccB = *reinterpret_cast<const float4*>(ctLds + si * kC + 4);
        const float4 csA = *reinterpret_cast<const float4*>(shLds + si * kC);
        const float4 csB = *reinterpret_cast<const float4*>(shLds + si * kC + 4);
        const float ct[8] = {ccA.x, ccA.y, ccA.z, ccA.w, ccB.x, ccB.y, ccB.z, ccB.w};
        const float sh[8] = {csA.x, csA.y, csA.z, csA.w, csB.x, csB.y, csB.z, csB.w};
        float accA[4], accB[4];
        #pragma unroll
        for (int k = 0; k < 4; ++k) { accA[k] = 0.f; accB[k] = 0.f; }
        #pragma unroll
        for (int c = 0; c < kC; ++c) {
            const float fl = floorf(sh[c]);
            const float fr = sh[c] - fl;
            int d = (int)fl;
            d = d < -31 ? -31 : (d > 31 ? 31 : d);
            const float w1 = ct[c] * fr;
            const float w0 = ct[c] - w1;
            const int a   = 4 * t + d + kPadH;
            const int u0  = a >> 1;
            const bool odd = (a & 1) != 0;
            const uint32_t* row = ldsU + c * kRowStride;
            const uint32_t yA0 = row[swz(u0 + 0)];
            const uint32_t yA1 = row[swz(u0 + 1)];
            const uint32_t yA2 = row[swz(u0 + 2)];
            const uint32_t yB0 = row[swz(u0 + 512)];
            const uint32_t yB1 = row[swz(u0 + 513)];
            const uint32_t yB2 = row[swz(u0 + 514)];
            const uint32_t zA0 = odd ? __builtin_amdgcn_alignbit(yA1, yA0, 16) : yA0;
            const uint32_t zA1 = odd ? __builtin_amdgcn_alignbit(yA2, yA1, 16) : yA1;
            const uint32_t zA2 = odd ? (yA2 >> 16) : yA2;
            const uint32_t zB0 = odd ? __builtin_amdgcn_alignbit(yB1, yB0, 16) : yB0;
            const uint32_t zB1 = odd ? __builtin_amdgcn_alignbit(yB2, yB1, 16) : yB1;
            const uint32_t zB2 = odd ? (yB2 >> 16) : yB2;
            const float2 fA0 = __half22float2(*reinterpret_cast<const __half2*>(&zA0));
            const float2 fA1 = __half22float2(*reinterpret_cast<const __half2*>(&zA1));
            const float2 fA2 = __half22float2(*reinterpret_cast<const __half2*>(&zA2));
            const float2 fB0 = __half22float2(*reinterpret_cast<const __half2*>(&zB0));
            const float2 fB1 = __half22float2(*reinterpret_cast<const __half2*>(&zB1));
            const float2 fB2 = __half22float2(*reinterpret_cast<const __half2*>(&zB2));
            accA[0] += w0 * fA0.x + w1 * fA0.y;
            accA[1] += w0 * fA0.y + w1 * fA1.x;
            accA[2] += w0 * fA1.x + w1 * fA1.y;
            accA[3] += w0 * fA1.y + w1 * fA2.x;
            accB[0] += w0 * fB0.x + w1 * fB0.y;
            accB[1] += w0 * fB0.y + w1 * fB1.x;
            accB[2] += w0 * fB1.x + w1 * fB1.y;
            accB[3] += w0 * fB1.y + w1 * fB2.x;
        }
        float* orow = out + (size_t)s * kN;
        *reinterpret_cast<float4*>(orow + 4 * t) =
            make_float4(accA[0], accA[1], accA[2], accA[3]);
        *reinterpret_cast<float4*>(orow + 1024 + 4 * t) =
            make_float4(accB[0], accB[1], accB[2], accB[3]);
    }
}
} // namespace

extern "C" void kernel_launch(void* const* d_in, const int* in_sizes, int n_in,
                              void* d_out, int out_size, void* d_ws, size_t ws_size,
                              hipStream_t stream) {
    // inputs: [0]=inputs (unused), [1]=components, [2]=contributions, [3]=shift
    const float* comps   = (const float*)d_in[1];
    const float* contrib = (const float*)d_in[2];
    const float* shiftp  = (const float*)d_in[3];
    float* out = (float*)d_out;

    if (ws_size >= kWsNeed && d_ws != nullptr) {
        __half* Gt = (__half*)d_ws;
        buildG_kernel<<<dim3((kC * kN) / 256), dim3(256), 0, stream>>>(comps, Gt);
        gemm_kernel<<<dim3(kS / 64), dim3(512), 0, stream>>>(contrib, shiftp, Gt, out);
    } else {
        smf_kernel<<<dim3(kS / kMf), dim3(kBlockF), 0, stream>>>(comps, contrib, shiftp, out);
    }
}

// Round 7
// 260.740 us; speedup vs baseline: 1.2301x; 1.1283x over previous
//
#include <hip/hip_runtime.h>
#include <hip/hip_fp16.h>

// R7: same GEMM math as R6 (refcheck-passed, absmax 0.03125), new schedule.
// R6 post-mortem: time (115us) is pinned independent of HBM traffic
// (R0..R6: 170-640 MB all ~115-133us). VALUBusy 2.6%, MfmaUtil 7%,
// occupancy 21% -> waves resident but idle: barrier-exposed latency.
// Each __syncthreads drains vmcnt(0) (incl. nontemporal HBM store acks),
// 3x per step, 1 block/CU -> no TLP to cover it.
// Fix (T3 minimum 2-phase, raw barriers):
//  - Btile double-buffered (panel 64 cols x 32 steps; 2x40KB + Atile 40KB
//    = 120KB LDS), stage buf^1 while computing buf;
//  - ONE raw s_barrier per step with only lgkmcnt(0) -- global stores are
//    NEVER drained (output never re-read; tb-reg RAW gets compiler-counted
//    vmcnt); sched_barrier(0) pins LDS ops at the barrier (rule #18);
//  - outB bounce dropped: direct per-lane dword stores (R4 vs R6 proved
//    store shape doesn't move the write counter or time).

namespace {
constexpr int kS = 16384;
constexpr int kN = 2048;
constexpr int kC = 8;
constexpr int kK = 320;             // 8 comps * 40 slots
constexpr int kSlots = 40;
constexpr size_t kGtBytes = (size_t)kN * kK * 2;   // 1,310,720
constexpr size_t kWsNeed  = kGtBytes;

typedef _Float16 f16x8 __attribute__((ext_vector_type(8)));
typedef float    f32x4 __attribute__((ext_vector_type(4)));

// ---------------- pre-kernel: build Gt[n][320] (R4-verified) ----------------
__global__ __launch_bounds__(256)
void buildG_kernel(const float* __restrict__ comps, __half* __restrict__ Gt) {
    const int tid = blockIdx.x * 256 + threadIdx.x;   // 0..16383
    const int c = tid >> 11;
    const int n = tid & 2047;
    const float* src = comps + c * kN;

    uint32_t w[kSlots / 2];
    #pragma unroll
    for (int t2 = 0; t2 < kSlots / 2; ++t2) {
        uint32_t pk = 0;
        #pragma unroll
        for (int h = 0; h < 2; ++h) {
            const int t = 2 * t2 + h;
            float v = 0.f;
            if (t < 35) {
                const int j = n + (t - 17);
                if (j >= 0 && j < kN) v = src[j];
            }
            const __half hv = __float2half_rn(v);
            pk |= (uint32_t)__half_as_ushort(hv) << (16 * h);
        }
        w[t2] = pk;
    }
    uint4* dst = reinterpret_cast<uint4*>(Gt + (size_t)n * kK + c * kSlots);
    #pragma unroll
    for (int i = 0; i < kSlots / 8; ++i)
        dst[i] = make_uint4(w[4 * i], w[4 * i + 1], w[4 * i + 2], w[4 * i + 3]);
}

// ---------------- main kernel: 256 blocks x 512 threads ----------------
// Block: 64 s-rows x 2048 n-cols, 32 n-steps of 64 cols.
// Waves: 8 = 2m x 4n; wave tile 32 rows x 16 cols; frags 2mi x 1ni; K=320.
__global__ __launch_bounds__(512, 2)
void gemm_kernel(const float* __restrict__ contrib,
                 const float* __restrict__ shift,
                 const __half* __restrict__ Gt,
                 float* __restrict__ out)
{
    __shared__ __half Atile[64 * kK];      // 40960 B, slot-swizzled
    __shared__ __half Btile[2][64 * kK];   // 2x40960 B, slot-swizzled
    // total 122880 B -> 1 block/CU

    const int tid = threadIdx.x;
    const int s0  = blockIdx.x * 64;

    // staging map: rr = panel row (0..63), sb = 0..7; slots sb+8q, q=0..4.
    const int rr = tid >> 3;
    const int sb = tid & 7;
    uint4 tb[5];

    // ---- issue panel-0 loads early (T14) ----
    {
        const __half* g = Gt + (size_t)rr * kK;
        #pragma unroll
        for (int q = 0; q < 5; ++q)
            tb[q] = *reinterpret_cast<const uint4*>(g + (sb + 8 * q) * 8);
    }

    // ---- build A-tile in LDS (zero + scatter), swizzle as in R6 ----
    #pragma unroll
    for (int i = 0; i < 5; ++i)
        reinterpret_cast<uint4*>(Atile)[i * 512 + tid] = make_uint4(0u,0u,0u,0u);
    __syncthreads();
    {
        const int sr = tid >> 3;
        const int c  = tid & 7;
        const float ctv = contrib[(size_t)(s0 + sr) * kC + c];
        const float sv  = shift[(size_t)(s0 + sr) * kC + c];
        int d = (int)floorf(sv);
        d = d < -17 ? -17 : (d > 16 ? 16 : d);
        const float fr = sv - (float)d;
        const __half w1h = __float2half_rn(ctv * fr);
        const __half w0h = __float2half_rn(ctv - __half2float(w1h)); // compensated
        const int h0 = c * kSlots + d + 17;
        const int h1 = h0 + 1;
        const int x  = sr & 7;
        Atile[sr * kK + (((h0 >> 3) ^ x) << 3) + (h0 & 7)] = w0h;
        Atile[sr * kK + (((h1 >> 3) ^ x) << 3) + (h1 & 7)] = w1h;
    }
    __syncthreads();

    // ---- preload A-frags into regs (read once, reuse 32 steps) ----
    const int lane = tid & 63;
    const int wave = tid >> 6;
    const int wm = (wave >> 2) * 32;      // 0 / 32
    const int wn = (wave & 3) * 16;       // 0 / 16 / 32 / 48
    const int l15 = lane & 15, l4 = lane >> 4;

    f16x8 af[10][2];
    #pragma unroll
    for (int mi = 0; mi < 2; ++mi) {
        const int r = wm + mi * 16 + l15;
        const int x = r & 7;
        #pragma unroll
        for (int ks = 0; ks < 10; ++ks) {
            const int sl = (ks * 4 + l4) ^ x;
            af[ks][mi] = *reinterpret_cast<const f16x8*>(&Atile[r * kK + sl * 8]);
        }
    }

    // ---- stage panel 0 -> Btile[0] (compiler emits counted vmcnt for tb) ----
    {
        __half* drow = &Btile[0][rr * kK];
        #pragma unroll
        for (int q = 0; q < 5; ++q) {
            const int sl = (sb + 8 * q) ^ (rr & 7);
            *reinterpret_cast<uint4*>(drow + sl * 8) = tb[q];
        }
    }
    // issue panel-1 loads
    {
        const __half* g = Gt + ((size_t)64 + rr) * kK;
        #pragma unroll
        for (int q = 0; q < 5; ++q)
            tb[q] = *reinterpret_cast<const uint4*>(g + (sb + 8 * q) * 8);
    }
    asm volatile("s_waitcnt lgkmcnt(0)" ::: "memory");
    __builtin_amdgcn_s_barrier();
    __builtin_amdgcn_sched_barrier(0);

    // B-frag loop invariants
    const int rB = wn + l15;
    const int xB = rB & 7;
    const int bBase = rB * kK;

    #pragma unroll 1
    for (int step = 0; step < 32; ++step) {
        const int cur = step & 1;
        const int nxt = cur ^ 1;

        // phase 1: stage panel step+1 -> Btile[nxt] (tb RAW -> counted vmcnt)
        if (step < 31) {
            __half* drow = &Btile[nxt][rr * kK];
            #pragma unroll
            for (int q = 0; q < 5; ++q) {
                const int sl = (sb + 8 * q) ^ (rr & 7);
                *reinterpret_cast<uint4*>(drow + sl * 8) = tb[q];
            }
        }
        // phase 2: issue panel step+2 loads (WAR on tb: safe, in-order issue)
        if (step < 30) {
            const __half* g = Gt + ((size_t)(step + 2) * 64 + rr) * kK;
            #pragma unroll
            for (int q = 0; q < 5; ++q)
                tb[q] = *reinterpret_cast<const uint4*>(g + (sb + 8 * q) * 8);
        }

        // phase 3: K-loop — B from Btile[cur], A from regs
        f32x4 acc0 = {0.f,0.f,0.f,0.f};
        f32x4 acc1 = {0.f,0.f,0.f,0.f};
        #pragma unroll
        for (int ks = 0; ks < 10; ++ks) {
            const int kq = ks * 4 + l4;
            const f16x8 b = *reinterpret_cast<const f16x8*>(
                &Btile[cur][bBase + ((kq ^ xB) << 3)]);
            acc0 = __builtin_amdgcn_mfma_f32_16x16x32_f16(af[ks][0], b, acc0, 0,0,0);
            acc1 = __builtin_amdgcn_mfma_f32_16x16x32_f16(af[ks][1], b, acc1, 0,0,0);
        }

        // phase 4: direct stores (C/D: col=lane&15, row=(lane>>4)*4+v).
        // Never waited on inside the kernel.
        {
            float* col = out + (size_t)(step * 64 + wn + l15);
            const int r0 = s0 + wm + l4 * 4;
            #pragma unroll
            for (int v = 0; v < 4; ++v) {
                col[(size_t)(r0 + v) * kN]      = acc0[v];
                col[(size_t)(r0 + 16 + v) * kN] = acc1[v];
            }
        }

        // single per-step barrier: ds_writes visible, ds_reads of [cur]
        // already consumed by MFMA; stores stay in flight.
        asm volatile("s_waitcnt lgkmcnt(0)" ::: "memory");
        __builtin_amdgcn_s_barrier();
        __builtin_amdgcn_sched_barrier(0);
    }
}

// ---------------- R3 fallback (known-passing) ----------------
constexpr int kMf     = 16;
constexpr int kBlockF = 512;
constexpr int kPadH  = 32;
constexpr int kUnits = 1057;
constexpr int kRowStride = 1192;
__device__ __forceinline__ int swz(int u) { return u + (u >> 3); }

__global__ __launch_bounds__(kBlockF, 8)
void smf_kernel(const float* __restrict__ comps,
                const float* __restrict__ contrib,
                const float* __restrict__ shift,
                float* __restrict__ out)
{
    __shared__ uint32_t ldsU[kC * kRowStride];
    __shared__ float    ctLds[kMf * kC];
    __shared__ float    shLds[kMf * kC];

    const int tid = threadIdx.x;
    const int s0  = blockIdx.x * kMf;

    for (int c = 0; c < kC; ++c) {
        const float* src = comps + c * kN;
        uint32_t* dstp = ldsU + c * kRowStride;
        for (int u = tid; u < kUnits; u += kBlockF) {
            const int j = 2 * u - kPadH;
            float2 v = make_float2(0.f, 0.f);
            if (j >= 0 && j < kN - 1) v = *reinterpret_cast<const float2*>(src + j);
            __half2 h2 = __floats2half2_rn(v.x, v.y);
            dstp[swz(u)] = *reinterpret_cast<const uint32_t*>(&h2);
        }
    }
    for (int tt = tid; tt < (kMf * kC) / 2; tt += kBlockF) {
        if (tt < (kMf * kC) / 4) {
            reinterpret_cast<float4*>(ctLds)[tt] =
                reinterpret_cast<const float4*>(contrib + (size_t)s0 * kC)[tt];
        } else {
            const int t2 = tt - (kMf * kC) / 4;
            reinterpret_cast<float4*>(shLds)[t2] =
                reinterpret_cast<const float4*>(shift + (size_t)s0 * kC)[t2];
        }
    }
    __syncthreads();

    const int q = tid >> 8;
    const int t = tid & 255;

    #pragma unroll 1
    for (int r = 0; r < kMf / 2; ++r) {
        const int si = q * (kMf / 2) + r;
        const int s  = s0 + si;
        const float4 ccA = *reinterpret_cast<const float4*>(ctLds + si * kC);
        const float4 ccB = *reinterpret_cast<const float4*>(ctLds + si * kC + 4);
        const float4 csA = *reinterpret_cast<const float4*>(shLds + si * kC);
        const float4 csB = *reinterpret_cast<const float4*>(shLds + si * kC + 4);
        const float ct[8] = {ccA.x, ccA.y, ccA.z, ccA.w, ccB.x, ccB.y, ccB.z, ccB.w};
        const float sh[8] = {csA.x, csA.y, csA.z, csA.w, csB.x, csB.y, csB.z, csB.w};
        float accA[4], accB[4];
        #pragma unroll
        for (int k = 0; k < 4; ++k) { accA[k] = 0.f; accB[k] = 0.f; }
        #pragma unroll
        for (int c = 0; c < kC; ++c) {
            const float fl = floorf(sh[c]);
            const float fr = sh[c] - fl;
            int d = (int)fl;
            d = d < -31 ? -31 : (d > 31 ? 31 : d);
            const float w1 = ct[c] * fr;
            const float w0 = ct[c] - w1;
            const int a   = 4 * t + d + kPadH;
            const int u0  = a >> 1;
            const bool odd = (a & 1) != 0;
            const uint32_t* row = ldsU + c * kRowStride;
            const uint32_t yA0 = row[swz(u0 + 0)];
            const uint32_t yA1 = row[swz(u0 + 1)];
            const uint32_t yA2 = row[swz(u0 + 2)];
            const uint32_t yB0 = row[swz(u0 + 512)];
            const uint32_t yB1 = row[swz(u0 + 513)];
            const uint32_t yB2 = row[swz(u0 + 514)];
            const uint32_t zA0 = odd ? __builtin_amdgcn_alignbit(yA1, yA0, 16) : yA0;
            const uint32_t zA1 = odd ? __builtin_amdgcn_alignbit(yA2, yA1, 16) : yA1;
            const uint32_t zA2 = odd ? (yA2 >> 16) : yA2;
            const uint32_t zB0 = odd ? __builtin_amdgcn_alignbit(yB1, yB0, 16) : yB0;
            const uint32_t zB1 = odd ? __builtin_amdgcn_alignbit(yB2, yB1, 16) : yB1;
            const uint32_t zB2 = odd ? (yB2 >> 16) : yB2;
            const float2 fA0 = __half22float2(*reinterpret_cast<const __half2*>(&zA0));
            const float2 fA1 = __half22float2(*reinterpret_cast<const __half2*>(&zA1));
            const float2 fA2 = __half22float2(*reinterpret_cast<const __half2*>(&zA2));
            const float2 fB0 = __half22float2(*reinterpret_cast<const __half2*>(&zB0));
            const float2 fB1 = __half22float2(*reinterpret_cast<const __half2*>(&zB1));
            const float2 fB2 = __half22float2(*reinterpret_cast<const __half2*>(&zB2));
            accA[0] += w0 * fA0.x + w1 * fA0.y;
            accA[1] += w0 * fA0.y + w1 * fA1.x;
            accA[2] += w0 * fA1.x + w1 * fA1.y;
            accA[3] += w0 * fA1.y + w1 * fA2.x;
            accB[0] += w0 * fB0.x + w1 * fB0.y;
            accB[1] += w0 * fB0.y + w1 * fB1.x;
            accB[2] += w0 * fB1.x + w1 * fB1.y;
            accB[3] += w0 * fB1.y + w1 * fB2.x;
        }
        float* orow = out + (size_t)s * kN;
        *reinterpret_cast<float4*>(orow + 4 * t) =
            make_float4(accA[0], accA[1], accA[2], accA[3]);
        *reinterpret_cast<float4*>(orow + 1024 + 4 * t) =
            make_float4(accB[0], accB[1], accB[2], accB[3]);
    }
}
} // namespace

extern "C" void kernel_launch(void* const* d_in, const int* in_sizes, int n_in,
                              void* d_out, int out_size, void* d_ws, size_t ws_size,
                              hipStream_t stream) {
    // inputs: [0]=inputs (unused), [1]=components, [2]=contributions, [3]=shift
    const float* comps   = (const float*)d_in[1];
    const float* contrib = (const float*)d_in[2];
    const float* shiftp  = (const float*)d_in[3];
    float* out = (float*)d_out;

    if (ws_size >= kWsNeed && d_ws != nullptr) {
        __half* Gt = (__half*)d_ws;
        buildG_kernel<<<dim3((kC * kN) / 256), dim3(256), 0, stream>>>(comps, Gt);
        gemm_kernel<<<dim3(kS / 64), dim3(512), 0, stream>>>(contrib, shiftp, Gt, out);
    } else {
        smf_kernel<<<dim3(kS / kMf), dim3(kBlockF), 0, stream>>>(comps, contrib, shiftp, out);
    }
}